// Round 4
// baseline (162.948 us; speedup 1.0000x reference)
//
#include <hip/hip_runtime.h>

typedef __bf16 bf16x8 __attribute__((ext_vector_type(8)));
typedef float f32x4 __attribute__((ext_vector_type(4)));
typedef unsigned int u32x4 __attribute__((ext_vector_type(4)));

__device__ __forceinline__ unsigned short f2bf(float f) {
  unsigned int u = __float_as_uint(f);
  u += 0x7FFFu + ((u >> 16) & 1u);   // round-to-nearest-even (matches all
  return (unsigned short)(u >> 16);  // previously-verified rounds exactly)
}

// Load 8 consecutive fp32 and pack to a bf16x8 MFMA fragment (in-register
// convert -- replaces the separate convert_all kernel / bf16 panels).
__device__ __forceinline__ bf16x8 cvt8(const float* __restrict__ p) {
  const float4 a = *(const float4*)p;
  const float4 b = *(const float4*)(p + 4);
  u32x4 v;
  v.x = ((unsigned)f2bf(a.y) << 16) | (unsigned)f2bf(a.x);
  v.y = ((unsigned)f2bf(a.w) << 16) | (unsigned)f2bf(a.z);
  v.z = ((unsigned)f2bf(b.y) << 16) | (unsigned)f2bf(b.x);
  v.w = ((unsigned)f2bf(b.w) << 16) | (unsigned)f2bf(b.z);
  return __builtin_bit_cast(bf16x8, v);
}

__device__ __forceinline__ bf16x8 zero8() {
  u32x4 v; v.x = 0; v.y = 0; v.z = 0; v.w = 0;
  return __builtin_bit_cast(bf16x8, v);
}

// Pin a fragment into VGPRs at this program point: defeats load-sink/remat
// (R2 evidence: VGPR_Count=76 < the 96 VGPRs of pinned A state). With fused
// fp32->bf16 conversion this is essential -- a remat would re-run ~200 pack
// ops per nt-iteration, not just reloads.
__device__ __forceinline__ void keep(bf16x8& x) {
  asm volatile("" : "+v"(x));
}

// ---------------------------------------------------------------------------
// t2i pooled score, fused fp32->bf16: TWO images per block vs one 16-caption
// group, A and B converted in-register from the fp32 sources.
//  * A rows o in [O, MT*16) are zero fragments (replaces the padded panel;
//    also avoids OOB reads past the source tensor).
//  * B needs no padding: the flattened (cap,word) row space is 16*W rows,
//    divisible by 16, and maps directly onto the row-major fp32 source.
//  * 1024-block parallel grid (R0 layout: latency-bound => max parallelism).
// Verified D mapping: col=lane&15 (B-row), row=(lane>>4)*4+reg (object).
// ---------------------------------------------------------------------------
template<int MT, int W, int O>
__device__ __forceinline__ void t2i_im2(
    const float* __restrict__ A,     // [128, O, 128] fp32
    const float* __restrict__ Bw,    // [128, W, 128] fp32 (flat 128*W rows)
    const int* __restrict__ obj_l, const int* __restrict__ cap_l,
    float* __restrict__ pooled,      // [128,128] fp32
    int vb, float* wmax)             // wmax LDS >= 2*16*W
{
  const int i0  = (vb >> 3) * 2;       // images 2*ig, 2*ig+1
  const int cg0 = (vb & 7) * 16;       // caption group base
  const int tid = threadIdx.x;
  const int wv = tid >> 6, lane = tid & 63;
  const int quad = lane >> 4, n16 = lane & 15;
  const int ol0 = obj_l[i0], ol1 = obj_l[i0 + 1];

  // ---- A fragments: load fp32 + convert ONCE, pin resident ----
  bf16x8 af[2][MT][4];
#pragma unroll
  for (int im = 0; im < 2; ++im)
#pragma unroll
    for (int t = 0; t < MT; ++t) {
      const int o = t * 16 + n16;
#pragma unroll
      for (int sf = 0; sf < 4; ++sf)
        af[im][t][sf] = (o < O)
            ? cvt8(A + (((size_t)(i0 + im) * O + o) << 7) + quad * 8 + sf * 32)
            : zero8();
    }
#pragma unroll
  for (int im = 0; im < 2; ++im)
#pragma unroll
    for (int t = 0; t < MT; ++t)
#pragma unroll
      for (int sf = 0; sf < 4; ++sf)
        keep(af[im][t][sf]);

  const float* Bbase = Bw + (((size_t)cg0 * W + n16) << 7) + quad * 8;

  // ---- prime B double-buffer ----
  bf16x8 bcur[4];
  {
    const float* bp = Bbase + ((size_t)(wv * 16) << 7);
#pragma unroll
    for (int sf = 0; sf < 4; ++sf) bcur[sf] = cvt8(bp + sf * 32);
  }

  for (int nt = wv; nt < W; nt += 4) {     // 16*W/16 = W tiles, exact
    // issue next-tile B loads (independent of this iteration's compute)
    const int ntn = (nt + 4 < W) ? (nt + 4) : wv;   // tail reload: harmless
    const float* bpn = Bbase + ((size_t)(ntn * 16) << 7);
    bf16x8 bnext[4];
#pragma unroll
    for (int sf = 0; sf < 4; ++sf) bnext[sf] = cvt8(bpn + sf * 32);

    f32x4 acc[2][MT];
#pragma unroll
    for (int im = 0; im < 2; ++im)
#pragma unroll
      for (int t = 0; t < MT; ++t) { f32x4 z = {0.f,0.f,0.f,0.f}; acc[im][t] = z; }
#pragma unroll
    for (int sf = 0; sf < 4; ++sf)
#pragma unroll
      for (int im = 0; im < 2; ++im)
#pragma unroll
        for (int t = 0; t < MT; ++t)
          acc[im][t] = __builtin_amdgcn_mfma_f32_16x16x32_bf16(
              af[im][t][sf], bcur[sf], acc[im][t], 0, 0, 0);

#pragma unroll
    for (int im = 0; im < 2; ++im) {
      const int ol = im ? ol1 : ol0;
      float m = -3.0e38f;
#pragma unroll
      for (int t = 0; t < MT; ++t)
#pragma unroll
        for (int r = 0; r < 4; ++r) {
          int o = t * 16 + quad * 4 + r;
          if (o < ol) m = fmaxf(m, acc[im][t][r]);
        }
      m = fmaxf(m, __shfl_xor(m, 16));
      m = fmaxf(m, __shfl_xor(m, 32));
      if (quad == 0) wmax[im * (16 * W) + nt * 16 + n16] = m;
    }

#pragma unroll
    for (int sf = 0; sf < 4; ++sf) bcur[sf] = bnext[sf];
  }
  __syncthreads();

  if (tid < 32) {
    const int im = tid >> 4, c = tid & 15;
    const float* wp = wmax + im * (16 * W) + c * W;
    float ssum = 0.f;
    for (int w = 0; w < W; ++w) ssum += wp[w];
    const int cc = cg0 + c;
    pooled[((i0 + im) << 7) + cc] = ssum / (float)cap_l[cc];
  }
}

// 1024 blocks, one part-slice each (R0's proven parallel layout).
__global__ __launch_bounds__(256, 2) void t2i_fused(
    const float* __restrict__ im,   const float* __restrict__ s,
    const float* __restrict__ pred, const float* __restrict__ crp,
    const int* __restrict__ im_l, const int* __restrict__ s_l,
    const int* __restrict__ pred_l, const int* __restrict__ crl,
    float* __restrict__ p1, float* __restrict__ p2)
{
  __shared__ float wmax[2 * 16 * 50];
  if (blockIdx.x < 512)
    t2i_im2<3, 50, 36>(im, s, im_l, s_l, p1, (int)blockIdx.x, wmax);
  else
    t2i_im2<2, 30, 25>(pred, crp, pred_l, crl, p2, (int)blockIdx.x - 512, wmax);
}

// ---------------------------------------------------------------------------
// Hinge loss, simplified form validated in R1/R2/R3:
//   max_j relu(M + S[i][j] - diag[i]) over the diag-zeroed matrix
//     == relu(M + offdiag_max_j(S[i][j]) - diag[i])
// One 256-thread block; kernel boundary provides p1/p2 coherence.
// ---------------------------------------------------------------------------
__global__ __launch_bounds__(256) void loss_kernel(
    const float* __restrict__ p1, const float* __restrict__ p2,
    float* __restrict__ out)
{
  __shared__ float cmax[2][128];
  __shared__ float rmax[2][128];
  __shared__ float wsum[2];
  const int tid = threadIdx.x;
  const int h = tid >> 7, j = tid & 127;

  // column off-diagonal max (coalesced: lanes sweep j for fixed row)
  {
    float cm = -3.0e38f;
    for (int rr = 0; rr < 64; ++rr) {
      const int row = h * 64 + rr;
      const float v = p1[row * 128 + j] + p2[row * 128 + j];
      cm = (row == j) ? cm : fmaxf(cm, v);
    }
    cmax[h][j] = cm;
  }
  // row off-diagonal max (thread (h, i=j) scans its 64-col half of row i)
  {
    float rm = -3.0e38f;
    for (int k = 0; k < 64; ++k) {
      const int c = h * 64 + k;
      const float v = p1[j * 128 + c] + p2[j * 128 + c];
      rm = (c == j) ? rm : fmaxf(rm, v);
    }
    rmax[h][j] = rm;
  }
  __syncthreads();

  float v = 0.f;
  if (tid < 128) {
    const float d  = p1[tid * 129] + p2[tid * 129];
    const float rm = fmaxf(rmax[0][tid], rmax[1][tid]);
    const float cm = fmaxf(cmax[0][tid], cmax[1][tid]);
    v = fmaxf(0.2f + rm - d, 0.f) + fmaxf(0.2f + cm - d, 0.f);
  }
#pragma unroll
  for (int o = 32; o; o >>= 1) v += __shfl_xor(v, o);
  if (tid == 0)  wsum[0] = v;
  if (tid == 64) wsum[1] = v;
  __syncthreads();
  if (tid == 0) out[0] = wsum[0] + wsum[1];
}

// ---------------------------------------------------------------------------
extern "C" void kernel_launch(void* const* d_in, const int* in_sizes, int n_in,
                              void* d_out, int out_size, void* d_ws, size_t ws_size,
                              hipStream_t stream)
{
  const float* im     = (const float*)d_in[0];
  const int*   im_l   = (const int*)  d_in[1];
  const float* s      = (const float*)d_in[2];
  const int*   s_l    = (const int*)  d_in[3];
  const float* pred   = (const float*)d_in[4];
  const int*   pred_l = (const int*)  d_in[5];
  // d_in[6], d_in[7] unused by the reference.
  const float* crp    = (const float*)d_in[8];
  const int*   crl    = (const int*)  d_in[9];

  char* ws = (char*)d_ws;
  float* p1 = (float*)ws;
  float* p2 = (float*)(ws + (size_t)128 * 128 * 4);

  hipLaunchKernelGGL(t2i_fused, dim3(1024), dim3(256), 0, stream,
                     im, s, pred, crp, im_l, s_l, pred_l, crl, p1, p2);
  hipLaunchKernelGGL(loss_kernel, dim3(1), dim3(256), 0, stream,
                     p1, p2, (float*)d_out);
}

// Round 5
// 139.926 us; speedup vs baseline: 1.1645x; 1.1645x over previous
//
#include <hip/hip_runtime.h>

typedef __bf16 bf16x8 __attribute__((ext_vector_type(8)));
typedef float f32x4 __attribute__((ext_vector_type(4)));
typedef unsigned int u32x4 __attribute__((ext_vector_type(4)));

__device__ __forceinline__ unsigned short f2bf(float f) {
  unsigned int u = __float_as_uint(f);
  u += 0x7FFFu + ((u >> 16) & 1u);   // round-to-nearest-even
  return (unsigned short)(u >> 16);
}

__device__ __forceinline__ bf16x8 load_frag(const unsigned short* p) {
  u32x4 v = *(const u32x4*)p;
  return __builtin_bit_cast(bf16x8, v);
}

// Pin a fragment into VGPRs at this program point (defeats load-sink/remat;
// R2 evidence: VGPR_Count=76 -> A reloads every nt iteration).
__device__ __forceinline__ void keep(bf16x8& x) {
  asm volatile("" : "+v"(x));
}

// ---------------------------------------------------------------------------
// fp32 -> bf16 conversion of all four tensors (object dim zero-padded to a
// multiple of 16 for MFMA M-tiling). Verified R0-R3. Measured path: bf16
// panels beat in-register fp32 convert by >20us (R4 post-mortem).
// ---------------------------------------------------------------------------
__global__ __launch_bounds__(256) void convert_all(
    const float* __restrict__ im, const float* __restrict__ s,
    const float* __restrict__ pred, const float* __restrict__ crp,
    unsigned short* __restrict__ imb, unsigned short* __restrict__ sb,
    unsigned short* __restrict__ pb, unsigned short* __restrict__ cb)
{
  int b = blockIdx.x;
  const float* src; unsigned short* dst; int O, OP, base;
  if (b < 768)       { src = im;   dst = imb; O = 36; OP = 48; base = 0; }
  else if (b < 1568) { src = s;    dst = sb;  O = 50; OP = 50; base = 768; }
  else if (b < 2080) { src = pred; dst = pb;  O = 25; OP = 32; base = 1568; }
  else               { src = crp;  dst = cb;  O = 30; OP = 30; base = 2080; }
  int tid = (b - base) * 256 + (int)threadIdx.x;          // one thread = 4 floats
  int total = 128 * OP * 32;
  if (tid >= total) return;
  int d4 = tid & 31;
  int o  = (tid >> 5) % OP;
  int bb = tid / (OP * 32);
  unsigned short r0 = 0, r1 = 0, r2 = 0, r3 = 0;
  if (o < O) {
    const float4 v = *(const float4*)(src + ((bb * O + o) << 7) + (d4 << 2));
    r0 = f2bf(v.x); r1 = f2bf(v.y); r2 = f2bf(v.z); r3 = f2bf(v.w);
  }
  ushort4 outv; outv.x = r0; outv.y = r1; outv.z = r2; outv.w = r3;
  *(ushort4*)(dst + (size_t)tid * 4) = outv;
}

// ---------------------------------------------------------------------------
// t2i pooled score, TWO images per block vs one 16-caption group.
// R5 structure:
//  * bf16 panels (measured fastest input path),
//  * A fragments loaded once + keep()-pinned,
//  * B tiles prefetched at distance 2 (triple buffer). To keep buffer
//    indices compile-time the nt-loop is FULLY UNROLLED (NITER = ceil(W/4));
//    waves whose last tile index exceeds W wrap around and recompute an
//    already-done tile -- deterministic identical value, benign same-word
//    LDS re-write, protected by the __syncthreads before any read.
// Verified D mapping: col=lane&15 (B-row), row=(lane>>4)*4+reg (object).
// ---------------------------------------------------------------------------
template<int MT, int W, int NITER>
__device__ __forceinline__ void t2i_im2(
    const unsigned short* __restrict__ A,    // [128, MT*16, 128] bf16
    const unsigned short* __restrict__ Bw,   // [128, W, 128] bf16 (flat rows)
    const int* __restrict__ obj_l, const int* __restrict__ cap_l,
    float* __restrict__ pooled,              // [128,128] fp32
    int vb, float* wmax)                     // wmax LDS >= 2*16*W
{
  const int i0  = (vb >> 3) * 2;       // images 2*ig, 2*ig+1
  const int cg0 = (vb & 7) * 16;       // caption group base
  const int tid = threadIdx.x;
  const int wv = tid >> 6, lane = tid & 63;
  const int quad = lane >> 4, n16 = lane & 15;
  const int ol0 = obj_l[i0], ol1 = obj_l[i0 + 1];

  // ---- A fragments: load once from bf16 panel, pin resident ----
  bf16x8 af[2][MT][4];
#pragma unroll
  for (int im = 0; im < 2; ++im) {
    const unsigned short* Ab =
        A + (((size_t)(i0 + im) * (MT * 16) + n16) << 7) + quad * 8;
#pragma unroll
    for (int t = 0; t < MT; ++t)
#pragma unroll
      for (int sf = 0; sf < 4; ++sf)
        af[im][t][sf] = load_frag(Ab + ((t * 16) << 7) + sf * 32);
  }
#pragma unroll
  for (int im = 0; im < 2; ++im)
#pragma unroll
    for (int t = 0; t < MT; ++t)
#pragma unroll
      for (int sf = 0; sf < 4; ++sf)
        keep(af[im][t][sf]);

  const unsigned short* Bbase = Bw + (((size_t)cg0 * W + n16) << 7) + quad * 8;

  // tile index of unrolled iteration `it` for this wave (wrap-around tail)
  auto ntof = [&](int it) {
    int nt = wv + it * 4;
    return (nt < W) ? nt : nt - W;
  };

  // ---- B triple buffer, prefetch distance 2 ----
  bf16x8 buf[3][4];
  {
    const unsigned short* p0 = Bbase + ((size_t)(ntof(0) * 16) << 7);
#pragma unroll
    for (int sf = 0; sf < 4; ++sf) buf[0][sf] = load_frag(p0 + sf * 32);
  }
  if (NITER > 1) {
    const unsigned short* p1 = Bbase + ((size_t)(ntof(1) * 16) << 7);
#pragma unroll
    for (int sf = 0; sf < 4; ++sf) buf[1][sf] = load_frag(p1 + sf * 32);
  }

#pragma unroll
  for (int it = 0; it < NITER; ++it) {
    if (it + 2 < NITER) {                    // issue tile it+2 (static index)
      const unsigned short* pn = Bbase + ((size_t)(ntof(it + 2) * 16) << 7);
#pragma unroll
      for (int sf = 0; sf < 4; ++sf)
        buf[(it + 2) % 3][sf] = load_frag(pn + sf * 32);
    }
    const int nt = ntof(it);

    f32x4 acc[2][MT];
#pragma unroll
    for (int im = 0; im < 2; ++im)
#pragma unroll
      for (int t = 0; t < MT; ++t) { f32x4 z = {0.f,0.f,0.f,0.f}; acc[im][t] = z; }
#pragma unroll
    for (int sf = 0; sf < 4; ++sf)
#pragma unroll
      for (int im = 0; im < 2; ++im)
#pragma unroll
        for (int t = 0; t < MT; ++t)
          acc[im][t] = __builtin_amdgcn_mfma_f32_16x16x32_bf16(
              af[im][t][sf], buf[it % 3][sf], acc[im][t], 0, 0, 0);

#pragma unroll
    for (int im = 0; im < 2; ++im) {
      const int ol = im ? ol1 : ol0;
      float m = -3.0e38f;
#pragma unroll
      for (int t = 0; t < MT; ++t)
#pragma unroll
        for (int r = 0; r < 4; ++r) {
          int o = t * 16 + quad * 4 + r;
          if (o < ol) m = fmaxf(m, acc[im][t][r]);
        }
      m = fmaxf(m, __shfl_xor(m, 16));
      m = fmaxf(m, __shfl_xor(m, 32));
      if (quad == 0) wmax[im * (16 * W) + nt * 16 + n16] = m;
    }
  }
  __syncthreads();

  if (tid < 32) {
    const int im = tid >> 4, c = tid & 15;
    const float* wp = wmax + im * (16 * W) + c * W;
    float ssum = 0.f;
    for (int w = 0; w < W; ++w) ssum += wp[w];
    const int cc = cg0 + c;
    pooled[((i0 + im) << 7) + cc] = ssum / (float)cap_l[cc];
  }
}

// 1024 blocks, one part-slice each (parallel layout measured ~2x faster
// than the 512-block serialized variant, R3 post-mortem).
__global__ __launch_bounds__(256, 2) void t2i_both(
    const unsigned short* __restrict__ imb, const unsigned short* __restrict__ sb,
    const unsigned short* __restrict__ pb,  const unsigned short* __restrict__ cb,
    const int* __restrict__ im_l, const int* __restrict__ s_l,
    const int* __restrict__ pred_l, const int* __restrict__ crl,
    float* __restrict__ p1, float* __restrict__ p2)
{
  __shared__ float wmax[2 * 16 * 50];
  if (blockIdx.x < 512)
    t2i_im2<3, 50, 13>(imb, sb, im_l, s_l, p1, (int)blockIdx.x, wmax);
  else
    t2i_im2<2, 30, 8>(pb, cb, pred_l, crl, p2, (int)blockIdx.x - 512, wmax);
}

// ---------------------------------------------------------------------------
// Hinge loss, simplified form validated in R1-R4:
//   max_j relu(M + S[i][j] - diag[i]) over the diag-zeroed matrix
//     == relu(M + offdiag_max_j(S[i][j]) - diag[i])
// One 256-thread block; kernel boundary provides p1/p2 coherence.
// ---------------------------------------------------------------------------
__global__ __launch_bounds__(256) void loss_kernel(
    const float* __restrict__ p1, const float* __restrict__ p2,
    float* __restrict__ out)
{
  __shared__ float cmax[2][128];
  __shared__ float rmax[2][128];
  __shared__ float wsum[2];
  const int tid = threadIdx.x;
  const int h = tid >> 7, j = tid & 127;

  // column off-diagonal max (coalesced: lanes sweep j for fixed row)
  {
    float cm = -3.0e38f;
    for (int rr = 0; rr < 64; ++rr) {
      const int row = h * 64 + rr;
      const float v = p1[row * 128 + j] + p2[row * 128 + j];
      cm = (row == j) ? cm : fmaxf(cm, v);
    }
    cmax[h][j] = cm;
  }
  // row off-diagonal max (thread (h, i=j) scans its 64-col half of row i)
  {
    float rm = -3.0e38f;
    for (int k = 0; k < 64; ++k) {
      const int c = h * 64 + k;
      const float v = p1[j * 128 + c] + p2[j * 128 + c];
      rm = (c == j) ? rm : fmaxf(rm, v);
    }
    rmax[h][j] = rm;
  }
  __syncthreads();

  float v = 0.f;
  if (tid < 128) {
    const float d  = p1[tid * 129] + p2[tid * 129];
    const float rm = fmaxf(rmax[0][tid], rmax[1][tid]);
    const float cm = fmaxf(cmax[0][tid], cmax[1][tid]);
    v = fmaxf(0.2f + rm - d, 0.f) + fmaxf(0.2f + cm - d, 0.f);
  }
#pragma unroll
  for (int o = 32; o; o >>= 1) v += __shfl_xor(v, o);
  if (tid == 0)  wsum[0] = v;
  if (tid == 64) wsum[1] = v;
  __syncthreads();
  if (tid == 0) out[0] = wsum[0] + wsum[1];
}

// ---------------------------------------------------------------------------
extern "C" void kernel_launch(void* const* d_in, const int* in_sizes, int n_in,
                              void* d_out, int out_size, void* d_ws, size_t ws_size,
                              hipStream_t stream)
{
  const float* im     = (const float*)d_in[0];
  const int*   im_l   = (const int*)  d_in[1];
  const float* s      = (const float*)d_in[2];
  const int*   s_l    = (const int*)  d_in[3];
  const float* pred   = (const float*)d_in[4];
  const int*   pred_l = (const int*)  d_in[5];
  // d_in[6], d_in[7] unused by the reference.
  const float* crp    = (const float*)d_in[8];
  const int*   crl    = (const int*)  d_in[9];

  char* ws = (char*)d_ws;
  const size_t off_imb = 0;
  const size_t off_sb  = off_imb + (size_t)128 * 48 * 128 * 2;
  const size_t off_pb  = off_sb  + (size_t)128 * 50 * 128 * 2;
  const size_t off_cb  = off_pb  + (size_t)128 * 32 * 128 * 2;
  const size_t off_p1  = off_cb  + (size_t)128 * 30 * 128 * 2;
  const size_t off_p2  = off_p1  + (size_t)128 * 128 * 4;

  unsigned short* imb = (unsigned short*)(ws + off_imb);
  unsigned short* sb  = (unsigned short*)(ws + off_sb);
  unsigned short* pb  = (unsigned short*)(ws + off_pb);
  unsigned short* cb  = (unsigned short*)(ws + off_cb);
  float* p1 = (float*)(ws + off_p1);
  float* p2 = (float*)(ws + off_p2);

  hipLaunchKernelGGL(convert_all, dim3(2560), dim3(256), 0, stream,
                     im, s, pred, crp, imb, sb, pb, cb);
  hipLaunchKernelGGL(t2i_both, dim3(1024), dim3(256), 0, stream,
                     imb, sb, pb, cb, im_l, s_l, pred_l, crl, p1, p2);
  hipLaunchKernelGGL(loss_kernel, dim3(1), dim3(256), 0, stream,
                     p1, p2, (float*)d_out);
}